// Round 1
// baseline (407.707 us; speedup 1.0000x reference)
//
#include <hip/hip_runtime.h>
#include <hip/hip_fp16.h>
#include <cstdint>
#include <cstddef>

#define B_ 8
#define S_ 4096
#define D_ 1024
#define H_ 512
#define M_ (B_*S_)

typedef __attribute__((ext_vector_type(8))) _Float16 half8;
typedef __attribute__((ext_vector_type(4))) float f4;

union HU { int4 v; half8 h; };

__device__ inline unsigned short f2h(float f){
  _Float16 h = (_Float16)f;
  return __builtin_bit_cast(unsigned short, h);
}

// ---------- init: zero accumulators, seed first/last ----------
__global__ void k_init(float* zb, int n, int* fl){
  int i = blockIdx.x*blockDim.x + threadIdx.x;
  for (; i < n; i += gridDim.x*blockDim.x) zb[i] = 0.f;
  if (blockIdx.x==0 && threadIdx.x==0){ fl[0] = 0x7FFFFFFF; fl[1] = -1; }
}

// ---------- W1^T in f16 (512 x 1024, k-contiguous rows) ----------
__global__ void k_w1t(const float* __restrict__ w1, unsigned short* __restrict__ w1t){
  __shared__ float tile[32][33];
  int n0 = blockIdx.x*32, k0 = blockIdx.y*32;
  int tx = threadIdx.x, ty = threadIdx.y;
  #pragma unroll
  for (int i=0;i<4;i++) tile[ty+8*i][tx] = w1[(size_t)(k0+ty+8*i)*H_ + n0+tx];
  __syncthreads();
  #pragma unroll
  for (int i=0;i<4;i++) w1t[(size_t)(n0+ty+8*i)*D_ + k0+tx] = f2h(tile[tx][ty+8*i]);
}

// ---------- per-row norm^2 and adjacent-row dot ----------
__global__ void k_normdot(const float* __restrict__ X, float* __restrict__ n2o,
                          float* __restrict__ dto){
  int wave = threadIdx.x>>6, lane = threadIdx.x&63;
  int g0 = (blockIdx.x*4 + wave)*16;
  const float4* Xv = (const float4*)X;
  float4 pv[4];
  if ((g0 & (S_-1)) != 0){
    size_t bb = (size_t)(g0-1)*256;
    #pragma unroll
    for (int q=0;q<4;q++) pv[q] = Xv[bb + q*64 + lane];
  } else {
    #pragma unroll
    for (int q=0;q<4;q++) pv[q] = make_float4(0.f,0.f,0.f,0.f);
  }
  for (int r=0;r<16;r++){
    int g = g0 + r;
    size_t bb = (size_t)g*256;
    float4 cv[4];
    #pragma unroll
    for (int q=0;q<4;q++) cv[q] = Xv[bb + q*64 + lane];
    float n2=0.f, dp=0.f;
    #pragma unroll
    for (int q=0;q<4;q++){
      n2 += cv[q].x*cv[q].x + cv[q].y*cv[q].y + cv[q].z*cv[q].z + cv[q].w*cv[q].w;
      dp += pv[q].x*cv[q].x + pv[q].y*cv[q].y + pv[q].z*cv[q].z + pv[q].w*cv[q].w;
    }
    #pragma unroll
    for (int off=32; off>0; off>>=1){
      n2 += __shfl_down(n2, off);
      dp += __shfl_down(dp, off);
    }
    if (lane==0){
      n2o[g] = n2;
      if ((g & (S_-1)) != 0) dto[g-1] = dp;
    }
    #pragma unroll
    for (int q=0;q<4;q++) pv[q] = cv[q];
  }
}

// ---------- fused EOS MLP: logit[m] += sum_n w2[n]*relu((X@W1)[m,n]+b1[n]) ----------
#define AS1 __attribute__((address_space(1)))
#define AS3 __attribute__((address_space(3)))

__global__ __launch_bounds__(256) void k_mlp(const float* __restrict__ X,
    const unsigned short* __restrict__ W1T, const float* __restrict__ b1,
    const float* __restrict__ w2, float* __restrict__ logit){
  __shared__ __align__(16) unsigned short As[128*32];
  __shared__ __align__(16) unsigned short Bs[128*32];
  int tid = threadIdx.x;
  int wave = tid>>6, lane = tid&63, quad = lane>>4, l15 = lane&15;
  int m0 = blockIdx.x*128, n0 = blockIdx.y*128;
  int wm = (wave>>1)*64, wn = (wave&1)*64;
  f4 acc[4][4] = {};

  // A staging: 2 threads per row, 16 f32 each -> f16 ds_write
  int ar = tid>>1, ah = tid&1;
  const float* agp = X + (size_t)(m0+ar)*D_ + ah*16;
  ushort4* adst = (ushort4*)(As + ar*32 + ah*16);

  // B staging: global_load_lds width 16; chunk c = wave*2+it covers rows c*16..c*16+15
  const unsigned short* bgp0 = W1T + (size_t)(n0 + wave*32 + (lane>>2))*D_ + (lane&3)*8;
  const unsigned short* bgp1 = bgp0 + (size_t)16*D_;
  char* bl0 = (char*)Bs + (wave*2+0)*1024;
  char* bl1 = (char*)Bs + (wave*2+1)*1024;

  for (int kt=0; kt<32; ++kt){
    int k0 = kt*32;
    __builtin_amdgcn_global_load_lds((const AS1 void*)(bgp0 + k0), (AS3 void*)bl0, 16, 0, 0);
    __builtin_amdgcn_global_load_lds((const AS1 void*)(bgp1 + k0), (AS3 void*)bl1, 16, 0, 0);
    #pragma unroll
    for (int q=0;q<4;q++){
      float4 f = *(const float4*)(agp + k0 + 4*q);
      ushort4 u;
      u.x = f2h(f.x); u.y = f2h(f.y); u.z = f2h(f.z); u.w = f2h(f.w);
      adst[q] = u;
    }
    __syncthreads();
    HU a[4], b[4];
    const int4* As4 = (const int4*)As;
    const int4* Bs4 = (const int4*)Bs;
    #pragma unroll
    for (int i=0;i<4;i++) a[i].v = As4[(wm + 16*i + l15)*4 + quad];
    #pragma unroll
    for (int j=0;j<4;j++) b[j].v = Bs4[(wn + 16*j + l15)*4 + quad];
    #pragma unroll
    for (int i=0;i<4;i++){
      #pragma unroll
      for (int j=0;j<4;j++){
        acc[i][j] = __builtin_amdgcn_mfma_f32_16x16x32_f16(a[i].h, b[j].h, acc[i][j], 0, 0, 0);
      }
    }
    __syncthreads();
  }

  // epilogue: relu + w2-weighted reduction over this block's 128 columns
  float b1v[4], w2v[4];
  #pragma unroll
  for (int j=0;j<4;j++){
    int n = n0 + wn + 16*j + l15;
    b1v[j] = b1[n]; w2v[j] = w2[n];
  }
  #pragma unroll
  for (int i=0;i<4;i++){
    #pragma unroll
    for (int reg=0; reg<4; reg++){
      float p = 0.f;
      #pragma unroll
      for (int j=0;j<4;j++){
        float h = acc[i][j][reg] + b1v[j];
        h = fmaxf(h, 0.f);
        p += w2v[j]*h;
      }
      p += __shfl_xor(p, 1);
      p += __shfl_xor(p, 2);
      p += __shfl_xor(p, 4);
      p += __shfl_xor(p, 8);
      if (l15 == 0) atomicAdd(&logit[m0 + wm + 16*i + quad*4 + reg], p);
    }
  }
}

// ---------- per-chunk mask prefix counts ----------
__global__ void k_chunkbase(const int* __restrict__ mask, int* __restrict__ cb){
  __shared__ int sc[256];
  int b = blockIdx.x, t = threadIdx.x;
  const int* mrow = mask + (size_t)b*S_ + t*16;
  int s = 0;
  #pragma unroll
  for (int i=0;i<16;i++) s += mrow[i];
  sc[t] = s;
  __syncthreads();
  for (int off=1; off<256; off<<=1){
    int v = (t>=off) ? sc[t-off] : 0;
    __syncthreads();
    sc[t] += v;
    __syncthreads();
  }
  if ((t & 15) == 0) cb[b*16 + (t>>4)] = (t==0) ? 0 : sc[t-1];
}

// ---------- segment pooling (chunks with seg>=8 at entry exit early) ----------
__global__ void k_pool(const float* __restrict__ X, const int* __restrict__ mask,
                       const int* __restrict__ cb, float* __restrict__ gsums,
                       float* __restrict__ gcnt){
  int c = blockIdx.x, b = blockIdx.y, tid = threadIdx.x;
  int base = cb[b*16 + c];
  if (base >= 8) return;
  __shared__ float lsum[8*1024];
  __shared__ int seg[256];
  __shared__ float lcnt[8];
  __shared__ int send_s;
  for (int e=tid; e<8192; e+=256) lsum[e] = 0.f;
  if (tid==0){
    float cnts[8] = {0,0,0,0,0,0,0,0};
    const int* mrow = mask + (size_t)b*S_ + c*256;
    int running = base, i = 0;
    for (; i<256; ++i){
      if (running >= 8) break;
      seg[i] = running;
      cnts[running] += 1.f;
      running += mrow[i];
    }
    send_s = i;
    #pragma unroll
    for (int p=0;p<8;p++) lcnt[p] = cnts[p];
  }
  __syncthreads();
  int send = send_s;
  for (int s2=0; s2<send; ++s2){
    int sg = seg[s2];
    size_t gb = ((size_t)(b*S_ + c*256 + s2))*D_;
    #pragma unroll
    for (int q=0;q<4;q++){
      int d = tid + q*256;
      lsum[sg*1024 + d] += X[gb + d];
    }
  }
  __syncthreads();
  for (int e=tid; e<8192; e+=256){
    float v = lsum[e];
    if (v != 0.f) atomicAdd(&gsums[(size_t)b*8192 + e], v);
  }
  if (tid < 8){
    float v = lcnt[tid];
    if (v != 0.f) atomicAdd(&gcnt[b*8 + tid], v);
  }
}

// ---------- patches = pooled @ proj_w + proj_b ----------
__global__ void k_patch(const float* __restrict__ gsums, const float* __restrict__ gcnt,
                        const float* __restrict__ pw, const float* __restrict__ pb,
                        float* __restrict__ out){
  __shared__ float pool[8192];
  int b = blockIdx.y, cx = blockIdx.x, tid = threadIdx.x;
  for (int e=tid; e<8192; e+=64){
    float cnt = gcnt[b*8 + (e>>10)];
    pool[e] = gsums[(size_t)b*8192 + e] / fmaxf(cnt, 1.f);
  }
  __syncthreads();
  int col = cx*64 + tid;
  float acc[8] = {0,0,0,0,0,0,0,0};
  for (int k=0;k<1024;k++){
    float w = pw[(size_t)k*D_ + col];
    #pragma unroll
    for (int p=0;p<8;p++) acc[p] += pool[p*1024 + k]*w;
  }
  float bias = pb[col];
  #pragma unroll
  for (int p=0;p<8;p++) out[(size_t)(b*8+p)*D_ + col] = acc[p] + bias;
}

// ---------- flags + first/last reduction ----------
__global__ void k_flags(const float* __restrict__ logit, const float* __restrict__ n2,
                        const float* __restrict__ dt, const float* __restrict__ b2p,
                        int* __restrict__ fl){
  int g = blockIdx.x*256 + threadIdx.x;
  float b2 = b2p[0];
  int s = g & (S_-1);
  bool any = false;
  if (s >= 2){
    float z0 = logit[g] + b2;
    float z1 = logit[g-1] + b2;
    float z2 = logit[g-2] + b2;
    const float THR = 0.8472978603872037f;  // ln(0.7/0.3)
    bool run = (z0 > THR) & (z1 > THR) & (z2 > THR);
    float na = fmaxf(sqrtf(n2[g-1]), 1e-8f);
    float nb = fmaxf(sqrtf(n2[g]), 1e-8f);
    bool cosr = (dt[g-1] < 0.3f*na*nb) & (z0 > 0.f);
    any = run | cosr;
  }
  int mn = any ? s : 0x7FFFFFFF;
  int mx = any ? s : -1;
  #pragma unroll
  for (int off=32; off>0; off>>=1){
    mn = min(mn, __shfl_down(mn, off));
    mx = max(mx, __shfl_down(mx, off));
  }
  if ((threadIdx.x & 63) == 0){
    atomicMin(&fl[0], mn);
    atomicMax(&fl[1], mx);
  }
}

__global__ void k_bounds(const int* __restrict__ fl, float* __restrict__ ob){
  int f = fl[0], l = fl[1];
  if (l < 0){ ob[0] = -1.f; ob[1] = -1.f; }
  else {
    int st = f - 2; if (st < 0) st = 0;
    int en = l + 2; if (en > S_-1) en = S_-1;
    ob[0] = (float)st; ob[1] = (float)en;
  }
}

extern "C" void kernel_launch(void* const* d_in, const int* in_sizes, int n_in,
                              void* d_out, int out_size, void* d_ws, size_t ws_size,
                              hipStream_t stream){
  const float* latent = (const float*)d_in[0];
  const int*   mask   = (const int*)d_in[1];
  const float* proj_w = (const float*)d_in[2];
  const float* proj_b = (const float*)d_in[3];
  const float* eos_w1 = (const float*)d_in[4];
  const float* eos_b1 = (const float*)d_in[5];
  const float* eos_w2 = (const float*)d_in[6];
  const float* eos_b2 = (const float*)d_in[7];
  float* out = (float*)d_out;

  char* ws = (char*)d_ws;
  unsigned short* W1T = (unsigned short*)ws;     // 512*1024*2 = 1 MB
  float* fbase = (float*)(ws + 1048576);
  float* logit = fbase;                          // 32768
  float* norm2 = fbase + 32768;                  // 32768
  float* dotv  = fbase + 65536;                  // 32768
  float* gsums = fbase + 98304;                  // 65536
  float* gcnt  = fbase + 163840;                 // 64
  int* chunkbase = (int*)(fbase + 163904);       // 128
  int* firstlast = (int*)(fbase + 164032);       // 2

  k_init<<<256, 256, 0, stream>>>(fbase, 163904, firstlast);
  k_w1t<<<dim3(16,32), dim3(32,8), 0, stream>>>(eos_w1, W1T);
  k_normdot<<<512, 256, 0, stream>>>(latent, norm2, dotv);
  k_chunkbase<<<8, 256, 0, stream>>>(mask, chunkbase);
  k_pool<<<dim3(16,8), 256, 0, stream>>>(latent, mask, chunkbase, gsums, gcnt);
  k_patch<<<dim3(16,8), 64, 0, stream>>>(gsums, gcnt, proj_w, proj_b, out);
  k_mlp<<<dim3(256,4), 256, 0, stream>>>(latent, W1T, eos_b1, eos_w2, logit);
  k_flags<<<128, 256, 0, stream>>>(logit, norm2, dotv, eos_b2, firstlast);
  k_bounds<<<1,1,0,stream>>>(firstlast, out + 65536);
}

// Round 2
// 315.777 us; speedup vs baseline: 1.2911x; 1.2911x over previous
//
#include <hip/hip_runtime.h>
#include <hip/hip_fp16.h>
#include <cstdint>
#include <cstddef>

#define B_ 8
#define S_ 4096
#define D_ 1024
#define H_ 512
#define M_ (B_*S_)

typedef __attribute__((ext_vector_type(8))) _Float16 half8;
typedef __attribute__((ext_vector_type(4))) float f4;

union HU { int4 v; half8 h; };

__device__ inline unsigned short f2h(float f){
  _Float16 h = (_Float16)f;
  return __builtin_bit_cast(unsigned short, h);
}

// ---------- init: zero accumulators, seed first/last ----------
__global__ void k_init(float* zb, int n, int* fl){
  int i = blockIdx.x*blockDim.x + threadIdx.x;
  for (; i < n; i += gridDim.x*blockDim.x) zb[i] = 0.f;
  if (blockIdx.x==0 && threadIdx.x==0){ fl[0] = 0x7FFFFFFF; fl[1] = -1; }
}

// ---------- W1^T in f16 (512 x 1024, k-contiguous rows) ----------
__global__ void k_w1t(const float* __restrict__ w1, unsigned short* __restrict__ w1t){
  __shared__ float tile[32][33];
  int n0 = blockIdx.x*32, k0 = blockIdx.y*32;
  int tx = threadIdx.x, ty = threadIdx.y;
  #pragma unroll
  for (int i=0;i<4;i++) tile[ty+8*i][tx] = w1[(size_t)(k0+ty+8*i)*H_ + n0+tx];
  __syncthreads();
  #pragma unroll
  for (int i=0;i<4;i++) w1t[(size_t)(n0+ty+8*i)*D_ + k0+tx] = f2h(tile[tx][ty+8*i]);
}

// ---------- per-row norm^2, adjacent-row dot, AND fp32->f16 cast of X ----------
__global__ void k_normdot(const float* __restrict__ X, float* __restrict__ n2o,
                          float* __restrict__ dto, unsigned short* __restrict__ Xh){
  int wave = threadIdx.x>>6, lane = threadIdx.x&63;
  int g0 = (blockIdx.x*4 + wave)*16;
  const float4* Xv = (const float4*)X;
  ushort4* Xhv = (ushort4*)Xh;
  float4 pv[4];
  if ((g0 & (S_-1)) != 0){
    size_t bb = (size_t)(g0-1)*256;
    #pragma unroll
    for (int q=0;q<4;q++) pv[q] = Xv[bb + q*64 + lane];
  } else {
    #pragma unroll
    for (int q=0;q<4;q++) pv[q] = make_float4(0.f,0.f,0.f,0.f);
  }
  for (int r=0;r<16;r++){
    int g = g0 + r;
    size_t bb = (size_t)g*256;
    float4 cv[4];
    #pragma unroll
    for (int q=0;q<4;q++) cv[q] = Xv[bb + q*64 + lane];
    float n2=0.f, dp=0.f;
    #pragma unroll
    for (int q=0;q<4;q++){
      n2 += cv[q].x*cv[q].x + cv[q].y*cv[q].y + cv[q].z*cv[q].z + cv[q].w*cv[q].w;
      dp += pv[q].x*cv[q].x + pv[q].y*cv[q].y + pv[q].z*cv[q].z + pv[q].w*cv[q].w;
    }
    #pragma unroll
    for (int q=0;q<4;q++){
      ushort4 u;
      u.x = f2h(cv[q].x); u.y = f2h(cv[q].y); u.z = f2h(cv[q].z); u.w = f2h(cv[q].w);
      Xhv[bb + q*64 + lane] = u;
    }
    #pragma unroll
    for (int off=32; off>0; off>>=1){
      n2 += __shfl_down(n2, off);
      dp += __shfl_down(dp, off);
    }
    if (lane==0){
      n2o[g] = n2;
      if ((g & (S_-1)) != 0) dto[g-1] = dp;
    }
    #pragma unroll
    for (int q=0;q<4;q++) pv[q] = cv[q];
  }
}

// ---------- fused EOS MLP: logit[m] += sum_n w2[n]*relu((X@W1)[m,n]+b1[n]) ----------
#define AS1 __attribute__((address_space(1)))
#define AS3 __attribute__((address_space(3)))

__global__ __launch_bounds__(256) void k_mlp(const unsigned short* __restrict__ Xh,
    const unsigned short* __restrict__ W1T, const float* __restrict__ b1,
    const float* __restrict__ w2, float* __restrict__ logit){
  __shared__ __align__(16) unsigned short As[128*32];
  __shared__ __align__(16) unsigned short Bs[128*32];
  int tid = threadIdx.x;
  int wave = tid>>6, lane = tid&63, quad = lane>>4, l15 = lane&15;
  int m0 = blockIdx.x*128, n0 = blockIdx.y*128;
  int wm = (wave>>1)*64, wn = (wave&1)*64;
  f4 acc[4][4] = {};

  // Both operands staged via global_load_lds width-16.
  // Chunk c covers 16 rows (c*16..c*16+15), 64 B each; wave w owns chunks {2w, 2w+1}.
  const unsigned short* agp0 = Xh  + (size_t)(m0 + wave*32 + (lane>>2))*D_ + (lane&3)*8;
  const unsigned short* agp1 = agp0 + (size_t)16*D_;
  const unsigned short* bgp0 = W1T + (size_t)(n0 + wave*32 + (lane>>2))*D_ + (lane&3)*8;
  const unsigned short* bgp1 = bgp0 + (size_t)16*D_;
  char* al0 = (char*)As + (wave*2+0)*1024;
  char* al1 = (char*)As + (wave*2+1)*1024;
  char* bl0 = (char*)Bs + (wave*2+0)*1024;
  char* bl1 = (char*)Bs + (wave*2+1)*1024;

  for (int kt=0; kt<32; ++kt){
    int k0 = kt*32;
    __builtin_amdgcn_global_load_lds((const AS1 void*)(agp0 + k0), (AS3 void*)al0, 16, 0, 0);
    __builtin_amdgcn_global_load_lds((const AS1 void*)(agp1 + k0), (AS3 void*)al1, 16, 0, 0);
    __builtin_amdgcn_global_load_lds((const AS1 void*)(bgp0 + k0), (AS3 void*)bl0, 16, 0, 0);
    __builtin_amdgcn_global_load_lds((const AS1 void*)(bgp1 + k0), (AS3 void*)bl1, 16, 0, 0);
    __syncthreads();
    HU a[4], b[4];
    const int4* As4 = (const int4*)As;
    const int4* Bs4 = (const int4*)Bs;
    #pragma unroll
    for (int i=0;i<4;i++) a[i].v = As4[(wm + 16*i + l15)*4 + quad];
    #pragma unroll
    for (int j=0;j<4;j++) b[j].v = Bs4[(wn + 16*j + l15)*4 + quad];
    #pragma unroll
    for (int i=0;i<4;i++){
      #pragma unroll
      for (int j=0;j<4;j++){
        acc[i][j] = __builtin_amdgcn_mfma_f32_16x16x32_f16(a[i].h, b[j].h, acc[i][j], 0, 0, 0);
      }
    }
    __syncthreads();
  }

  // epilogue: relu + w2-weighted reduction over this block's 128 columns
  float b1v[4], w2v[4];
  #pragma unroll
  for (int j=0;j<4;j++){
    int n = n0 + wn + 16*j + l15;
    b1v[j] = b1[n]; w2v[j] = w2[n];
  }
  #pragma unroll
  for (int i=0;i<4;i++){
    #pragma unroll
    for (int reg=0; reg<4; reg++){
      float p = 0.f;
      #pragma unroll
      for (int j=0;j<4;j++){
        float h = acc[i][j][reg] + b1v[j];
        h = fmaxf(h, 0.f);
        p += w2v[j]*h;
      }
      p += __shfl_xor(p, 1);
      p += __shfl_xor(p, 2);
      p += __shfl_xor(p, 4);
      p += __shfl_xor(p, 8);
      if (l15 == 0) atomicAdd(&logit[m0 + wm + 16*i + quad*4 + reg], p);
    }
  }
}

// ---------- per-chunk mask prefix counts ----------
__global__ void k_chunkbase(const int* __restrict__ mask, int* __restrict__ cb){
  __shared__ int sc[256];
  int b = blockIdx.x, t = threadIdx.x;
  const int* mrow = mask + (size_t)b*S_ + t*16;
  int s = 0;
  #pragma unroll
  for (int i=0;i<16;i++) s += mrow[i];
  sc[t] = s;
  __syncthreads();
  for (int off=1; off<256; off<<=1){
    int v = (t>=off) ? sc[t-off] : 0;
    __syncthreads();
    sc[t] += v;
    __syncthreads();
  }
  if ((t & 15) == 0) cb[b*16 + (t>>4)] = (t==0) ? 0 : sc[t-1];
}

// ---------- segment pooling (chunks with seg>=8 at entry exit early) ----------
__global__ void k_pool(const float* __restrict__ X, const int* __restrict__ mask,
                       const int* __restrict__ cb, float* __restrict__ gsums,
                       float* __restrict__ gcnt){
  int c = blockIdx.x, b = blockIdx.y, tid = threadIdx.x;
  int base = cb[b*16 + c];
  if (base >= 8) return;
  __shared__ float lsum[8*1024];
  __shared__ int seg[256];
  __shared__ float lcnt[8];
  __shared__ int send_s;
  for (int e=tid; e<8192; e+=256) lsum[e] = 0.f;
  if (tid==0){
    float cnts[8] = {0,0,0,0,0,0,0,0};
    const int* mrow = mask + (size_t)b*S_ + c*256;
    int running = base, i = 0;
    for (; i<256; ++i){
      if (running >= 8) break;
      seg[i] = running;
      cnts[running] += 1.f;
      running += mrow[i];
    }
    send_s = i;
    #pragma unroll
    for (int p=0;p<8;p++) lcnt[p] = cnts[p];
  }
  __syncthreads();
  int send = send_s;
  for (int s2=0; s2<send; ++s2){
    int sg = seg[s2];
    size_t gb = ((size_t)(b*S_ + c*256 + s2))*D_;
    #pragma unroll
    for (int q=0;q<4;q++){
      int d = tid + q*256;
      lsum[sg*1024 + d] += X[gb + d];
    }
  }
  __syncthreads();
  for (int e=tid; e<8192; e+=256){
    float v = lsum[e];
    if (v != 0.f) atomicAdd(&gsums[(size_t)b*8192 + e], v);
  }
  if (tid < 8){
    float v = lcnt[tid];
    if (v != 0.f) atomicAdd(&gcnt[b*8 + tid], v);
  }
}

// ---------- patches = pooled @ proj_w + proj_b (k-split, latency-hiding) ----------
// grid (32, 8): 32 cols per block; block 256 = 8 kslices x 32 cols
__global__ __launch_bounds__(256) void k_patch(const float* __restrict__ gsums,
                        const float* __restrict__ gcnt,
                        const float* __restrict__ pw, const float* __restrict__ pb,
                        float* __restrict__ out){
  __shared__ float pool[8192];
  __shared__ float red[2048];
  int b = blockIdx.y, cx = blockIdx.x, tid = threadIdx.x;
  const float4* gs4 = (const float4*)(gsums + (size_t)b*8192);
  float4* pool4 = (float4*)pool;
  for (int e4=tid; e4<2048; e4+=256){
    int p = e4>>8;
    float inv = 1.f / fmaxf(gcnt[b*8 + p], 1.f);
    float4 v = gs4[e4];
    v.x*=inv; v.y*=inv; v.z*=inv; v.w*=inv;
    pool4[e4] = v;
  }
  __syncthreads();
  int c = tid & 31, ks = tid >> 5;
  int col = cx*32 + c;
  float acc[8] = {0,0,0,0,0,0,0,0};
  for (int k=ks*128; k<ks*128+128; ++k){
    float w = pw[(size_t)k*D_ + col];
    #pragma unroll
    for (int p=0;p<8;p++) acc[p] += pool[p*1024 + k]*w;
  }
  #pragma unroll
  for (int p=0;p<8;p++) red[tid*8 + p] = acc[p];
  __syncthreads();
  {
    int p = tid>>5, cc = tid&31;
    float s = 0.f;
    #pragma unroll
    for (int k2=0;k2<8;k2++) s += red[(k2*32 + cc)*8 + p];
    out[(size_t)(b*8+p)*D_ + cx*32 + cc] = s + pb[cx*32 + cc];
  }
}

// ---------- flags + first/last reduction ----------
__global__ void k_flags(const float* __restrict__ logit, const float* __restrict__ n2,
                        const float* __restrict__ dt, const float* __restrict__ b2p,
                        int* __restrict__ fl){
  int g = blockIdx.x*256 + threadIdx.x;
  float b2 = b2p[0];
  int s = g & (S_-1);
  bool any = false;
  if (s >= 2){
    float z0 = logit[g] + b2;
    float z1 = logit[g-1] + b2;
    float z2 = logit[g-2] + b2;
    const float THR = 0.8472978603872037f;  // ln(0.7/0.3)
    bool run = (z0 > THR) & (z1 > THR) & (z2 > THR);
    float na = fmaxf(sqrtf(n2[g-1]), 1e-8f);
    float nb = fmaxf(sqrtf(n2[g]), 1e-8f);
    bool cosr = (dt[g-1] < 0.3f*na*nb) & (z0 > 0.f);
    any = run | cosr;
  }
  int mn = any ? s : 0x7FFFFFFF;
  int mx = any ? s : -1;
  #pragma unroll
  for (int off=32; off>0; off>>=1){
    mn = min(mn, __shfl_down(mn, off));
    mx = max(mx, __shfl_down(mx, off));
  }
  if ((threadIdx.x & 63) == 0){
    atomicMin(&fl[0], mn);
    atomicMax(&fl[1], mx);
  }
}

__global__ void k_bounds(const int* __restrict__ fl, float* __restrict__ ob){
  int f = fl[0], l = fl[1];
  if (l < 0){ ob[0] = -1.f; ob[1] = -1.f; }
  else {
    int st = f - 2; if (st < 0) st = 0;
    int en = l + 2; if (en > S_-1) en = S_-1;
    ob[0] = (float)st; ob[1] = (float)en;
  }
}

extern "C" void kernel_launch(void* const* d_in, const int* in_sizes, int n_in,
                              void* d_out, int out_size, void* d_ws, size_t ws_size,
                              hipStream_t stream){
  const float* latent = (const float*)d_in[0];
  const int*   mask   = (const int*)d_in[1];
  const float* proj_w = (const float*)d_in[2];
  const float* proj_b = (const float*)d_in[3];
  const float* eos_w1 = (const float*)d_in[4];
  const float* eos_b1 = (const float*)d_in[5];
  const float* eos_w2 = (const float*)d_in[6];
  const float* eos_b2 = (const float*)d_in[7];
  float* out = (float*)d_out;

  char* ws = (char*)d_ws;
  unsigned short* W1T = (unsigned short*)ws;       // 512*1024*2 = 1 MB
  unsigned short* Xh  = (unsigned short*)(ws + 1048576); // 32768*1024*2 = 64 MB
  float* fbase = (float*)(ws + 1048576 + 67108864);
  float* logit = fbase;                            // 32768
  float* norm2 = fbase + 32768;                    // 32768
  float* dotv  = fbase + 65536;                    // 32768
  float* gsums = fbase + 98304;                    // 65536
  float* gcnt  = fbase + 163840;                   // 64
  int* chunkbase = (int*)(fbase + 163904);         // 128
  int* firstlast = (int*)(fbase + 164032);         // 2

  k_init<<<256, 256, 0, stream>>>(fbase, 163904, firstlast);
  k_w1t<<<dim3(16,32), dim3(32,8), 0, stream>>>(eos_w1, W1T);
  k_normdot<<<512, 256, 0, stream>>>(latent, norm2, dotv, Xh);
  k_chunkbase<<<8, 256, 0, stream>>>(mask, chunkbase);
  k_pool<<<dim3(16,8), 256, 0, stream>>>(latent, mask, chunkbase, gsums, gcnt);
  k_patch<<<dim3(32,8), 256, 0, stream>>>(gsums, gcnt, proj_w, proj_b, out);
  k_mlp<<<dim3(256,4), 256, 0, stream>>>(Xh, W1T, eos_b1, eos_w2, logit);
  k_flags<<<128, 256, 0, stream>>>(logit, norm2, dotv, eos_b2, firstlast);
  k_bounds<<<1,1,0,stream>>>(firstlast, out + 65536);
}